// Round 2
// baseline (14669.362 us; speedup 1.0000x reference)
//
#include <hip/hip_runtime.h>
#include <stdint.h>

// Problem constants
#define HH    1024
#define H3    3072
#define NB    8      // batch
#define SEQ   256
#define MTOK  2048   // B*S
#define VOCAB 32000
#define NWG   256    // persistent scan workgroups

typedef __attribute__((ext_vector_type(8))) short short8;
typedef __attribute__((ext_vector_type(4))) float floatx4;

__device__ __forceinline__ uint16_t f2bf(float f) {
    uint32_t u = __float_as_uint(f);
    return (uint16_t)((u + 0x7FFFu + ((u >> 16) & 1u)) >> 16);
}

__device__ __forceinline__ float sigm(float x) { return 1.0f / (1.0f + __expf(-x)); }

// ---------------------------------------------------------------------------
__global__ void kEmbed(const int* __restrict__ x, const float* __restrict__ emb,
                       uint16_t* __restrict__ xe) {
    int m = blockIdx.x;
    int tok = x[m];
    float4 v = *(const float4*)(emb + (size_t)tok * HH + threadIdx.x * 4);
    ushort4 o;
    o.x = f2bf(v.x); o.y = f2bf(v.y); o.z = f2bf(v.z); o.w = f2bf(v.w);
    *(ushort4*)(xe + (size_t)m * HH + threadIdx.x * 4) = o;
}

// fp32 [rows][stride] -> bf16 [rows][1024] (first 1024 cols)
__global__ void kConv(const float* __restrict__ src, uint16_t* __restrict__ dst,
                      int stride) {
    int row = blockIdx.x;
    float4 v = *(const float4*)(src + (size_t)row * stride + threadIdx.x * 4);
    ushort4 o;
    o.x = f2bf(v.x); o.y = f2bf(v.y); o.z = f2bf(v.z); o.w = f2bf(v.w);
    *(ushort4*)(dst + (size_t)row * HH + threadIdx.x * 4) = o;
}

// ---------------------------------------------------------------------------
// Tiled MFMA GEMM, bf16 A and bf16 W (both [*][1024]).
__global__ __launch_bounds__(256) void kGemm(
    const uint16_t* __restrict__ A, const uint16_t* __restrict__ W,
    const float* __restrict__ bias, float* __restrict__ C, int N) {
    __shared__ uint16_t lA[128 * 64];
    __shared__ uint16_t lB[128 * 64];

    const int tid  = threadIdx.x;
    const int rowT = blockIdx.y * 128;
    const int colT = blockIdx.x * 128;
    const int pos  = tid & 7;
    const int r8   = (tid >> 3) & 7;
    const int ca   = pos ^ r8;
    const int lane = tid & 63, w = tid >> 6;
    const int wm = (w >> 1) * 64, wn = (w & 1) * 64;
    const int l15 = lane & 15, l4 = lane >> 4;

    floatx4 acc[4][4];
    for (int a = 0; a < 4; a++)
        for (int b = 0; b < 4; b++)
            acc[a][b] = (floatx4){0.f, 0.f, 0.f, 0.f};

    for (int it = 0; it < 16; ++it) {
        const int kB = it * 64;
        uint4 av[4]; uint4 bv[4];
        for (int i = 0; i < 4; i++) {
            int row = i * 32 + (tid >> 3);
            av[i] = *(const uint4*)(A + (size_t)(rowT + row) * HH + kB + ca * 8);
            bv[i] = *(const uint4*)(W + (size_t)(colT + row) * HH + kB + ca * 8);
        }
        __syncthreads();
        for (int i = 0; i < 4; i++) {
            int slot = i * 256 + tid;
            *(uint4*)(lA + slot * 8) = av[i];
            *(uint4*)(lB + slot * 8) = bv[i];
        }
        __syncthreads();
        for (int ks = 0; ks < 2; ++ks) {
            short8 af[4], bf_[4];
            int kc = ks * 4 + l4;
            for (int mt = 0; mt < 4; mt++) {
                int row = wm + mt * 16 + l15;
                af[mt] = *(const short8*)(lA + row * 64 + ((kc ^ (row & 7)) * 8));
            }
            for (int nt = 0; nt < 4; nt++) {
                int row = wn + nt * 16 + l15;
                bf_[nt] = *(const short8*)(lB + row * 64 + ((kc ^ (row & 7)) * 8));
            }
            for (int mt = 0; mt < 4; mt++)
                for (int nt = 0; nt < 4; nt++)
                    acc[mt][nt] = __builtin_amdgcn_mfma_f32_16x16x32_bf16(
                        af[mt], bf_[nt], acc[mt][nt], 0, 0, 0);
        }
    }
    for (int nt = 0; nt < 4; nt++) {
        int col = colT + wn + nt * 16 + l15;
        float bval = bias[col];
        for (int mt = 0; mt < 4; mt++) {
            int row0 = rowT + wm + mt * 16 + l4 * 4;
            for (int r = 0; r < 4; r++)
                C[(size_t)(row0 + r) * N + col] = acc[mt][nt][r] + bval;
        }
    }
}

// Fallback GEMM: fp32 W converted on the fly (used if workspace too small).
__global__ __launch_bounds__(256) void kGemmF(
    const uint16_t* __restrict__ A, const float* __restrict__ W,
    const float* __restrict__ bias, float* __restrict__ C,
    int N, int strideW) {
    __shared__ uint16_t lA[128 * 64];
    __shared__ uint16_t lB[128 * 64];
    const int tid  = threadIdx.x;
    const int rowT = blockIdx.y * 128;
    const int colT = blockIdx.x * 128;
    const int pos  = tid & 7;
    const int r8   = (tid >> 3) & 7;
    const int ca   = pos ^ r8;
    const int lane = tid & 63, w = tid >> 6;
    const int wm = (w >> 1) * 64, wn = (w & 1) * 64;
    const int l15 = lane & 15, l4 = lane >> 4;
    floatx4 acc[4][4];
    for (int a = 0; a < 4; a++)
        for (int b = 0; b < 4; b++)
            acc[a][b] = (floatx4){0.f, 0.f, 0.f, 0.f};
    for (int it = 0; it < 16; ++it) {
        const int kB = it * 64;
        uint4 av[4]; uint4 bv[4];
        for (int i = 0; i < 4; i++) {
            int row = i * 32 + (tid >> 3);
            av[i] = *(const uint4*)(A + (size_t)(rowT + row) * HH + kB + ca * 8);
            const float* wp = W + (size_t)(colT + row) * strideW + kB + ca * 8;
            float4 w0 = *(const float4*)wp;
            float4 w1 = *(const float4*)(wp + 4);
            uint4 pk;
            pk.x = (uint32_t)f2bf(w0.x) | ((uint32_t)f2bf(w0.y) << 16);
            pk.y = (uint32_t)f2bf(w0.z) | ((uint32_t)f2bf(w0.w) << 16);
            pk.z = (uint32_t)f2bf(w1.x) | ((uint32_t)f2bf(w1.y) << 16);
            pk.w = (uint32_t)f2bf(w1.z) | ((uint32_t)f2bf(w1.w) << 16);
            bv[i] = pk;
        }
        __syncthreads();
        for (int i = 0; i < 4; i++) {
            int slot = i * 256 + tid;
            *(uint4*)(lA + slot * 8) = av[i];
            *(uint4*)(lB + slot * 8) = bv[i];
        }
        __syncthreads();
        for (int ks = 0; ks < 2; ++ks) {
            short8 af[4], bf_[4];
            int kc = ks * 4 + l4;
            for (int mt = 0; mt < 4; mt++) {
                int row = wm + mt * 16 + l15;
                af[mt] = *(const short8*)(lA + row * 64 + ((kc ^ (row & 7)) * 8));
            }
            for (int nt = 0; nt < 4; nt++) {
                int row = wn + nt * 16 + l15;
                bf_[nt] = *(const short8*)(lB + row * 64 + ((kc ^ (row & 7)) * 8));
            }
            for (int mt = 0; mt < 4; mt++)
                for (int nt = 0; nt < 4; nt++)
                    acc[mt][nt] = __builtin_amdgcn_mfma_f32_16x16x32_bf16(
                        af[mt], bf_[nt], acc[mt][nt], 0, 0, 0);
        }
    }
    for (int nt = 0; nt < 4; nt++) {
        int col = colT + wn + nt * 16 + l15;
        float bval = bias[col];
        for (int mt = 0; mt < 4; mt++) {
            int row0 = rowT + wm + mt * 16 + l4 * 4;
            for (int r = 0; r < 4; r++)
                C[(size_t)(row0 + r) * N + col] = acc[mt][nt][r] + bval;
        }
    }
}

// ---------------------------------------------------------------------------
// Reduce-scatter across 64 lanes; result for batch beta(lane) =
// ((lane&1)<<2) | (lane&2) | ((lane>>2)&1). 30 shuffles, static indexing only.
__device__ __forceinline__ float redScatter(float (&p)[NB], int lane) {
    float q[4];
#pragma unroll
    for (int i = 0; i < 4; i++) {
        float kk = (lane & 1) ? p[4 + i] : p[i];
        float ss = (lane & 1) ? p[i] : p[4 + i];
        q[i] = kk + __shfl_xor(ss, 1, 64);
    }
    float r[2];
#pragma unroll
    for (int i = 0; i < 2; i++) {
        float kk = (lane & 2) ? q[2 + i] : q[i];
        float ss = (lane & 2) ? q[i] : q[2 + i];
        r[i] = kk + __shfl_xor(ss, 2, 64);
    }
    float kk = (lane & 4) ? r[1] : r[0];
    float ss = (lane & 4) ? r[0] : r[1];
    float v = kk + __shfl_xor(ss, 4, 64);
    v += __shfl_xor(v, 8, 64);
    v += __shfl_xor(v, 16, 64);
    v += __shfl_xor(v, 32, 64);
    return v;
}

// ---------------------------------------------------------------------------
// Hand-rolled grid barrier (capture-safe; no cooperative launch).
// Release: fetch_add ACQ_REL agent -> buffer_wbl2 flushes XCD L2 to IF.
// Acquire: per-thread agent fence after exit -> buffer_inv (G16 coherence).
__device__ __forceinline__ void gbar(unsigned* cnt, unsigned* gen) {
    __syncthreads();   // WG stores drained (vmcnt 0) before arrive
    if (threadIdx.x == 0) {
        unsigned g = __hip_atomic_load(gen, __ATOMIC_RELAXED, __HIP_MEMORY_SCOPE_AGENT);
        unsigned a = __hip_atomic_fetch_add(cnt, 1u, __ATOMIC_ACQ_REL, __HIP_MEMORY_SCOPE_AGENT);
        if (a == NWG - 1u) {
            __hip_atomic_store(cnt, 0u, __ATOMIC_RELAXED, __HIP_MEMORY_SCOPE_AGENT);
            __hip_atomic_store(gen, g + 1u, __ATOMIC_RELEASE, __HIP_MEMORY_SCOPE_AGENT);
        } else {
            while (__hip_atomic_load(gen, __ATOMIC_RELAXED, __HIP_MEMORY_SCOPE_AGENT) == g)
                __builtin_amdgcn_s_sleep(1);
        }
    }
    __syncthreads();
    __builtin_amdgcn_fence(__ATOMIC_ACQUIRE, "agent");
}

// ---------------------------------------------------------------------------
// Persistent scan, normal launch. 256 WGs x 256 thr; capacity 2 WG/CU
// (64 KB LDS, VGPR<=256 via launch_bounds) => all 256 resident by capacity.
// Wave wv of WG w owns j = 4w+wv. l_Whh rows hoisted to 48 VGPRs (barrier
// acquire invalidates L2 every step; registers dodge the weight refetch).
__global__ __launch_bounds__(256, 2) void kScan(
    const float* __restrict__ lWih,   // [3072][2048]
    const float* __restrict__ lWhh,   // [3072][1024]
    const float* __restrict__ lbhh,
    const float* __restrict__ hWih, const float* __restrict__ hWhh,
    const float* __restrict__ hbih, const float* __restrict__ hbhh,
    const float* __restrict__ gix,    // [2048][3072]
    float* __restrict__ hL,           // [2][8][1024] ping-pong
    float* __restrict__ hH,           // [2][8][1024] ping-pong
    uint16_t* __restrict__ hs,        // [2048][1024] bf16
    unsigned* __restrict__ syncb)
{
    __shared__ float hsm[NB * HH];    // h_l broadcast (32 KB)
    __shared__ float hhm[NB * HH];    // h_h broadcast (32 KB)

    unsigned* cnt = syncb;
    unsigned* gen = syncb + 1;
    const int tid  = threadIdx.x;
    const int lane = tid & 63, wv = tid >> 6;
    const int j    = blockIdx.x * 4 + wv;
    const int beta = ((lane & 1) << 2) | (lane & 2) | ((lane >> 2) & 1);

    const float br  = lbhh[j], bz = lbhh[HH + j], bn = lbhh[2 * HH + j];
    const float hbr = hbih[j], hbz = hbih[HH + j], hbn = hbih[2 * HH + j];
    const float ghr = hbhh[j], ghz = hbhh[HH + j], ghn = hbhh[2 * HH + j];

    // hoist l_Whh rows {j, H+j, 2H+j} into registers (12 x float4 / lane)
    const float* wr_l = lWhh + (size_t)j * HH;
    const float* wz_l = lWhh + (size_t)(HH + j) * HH;
    const float* wn_l = lWhh + (size_t)(2 * HH + j) * HH;
    float4 wvr[4], wvz[4], wvn[4];
#pragma unroll
    for (int c = 0; c < 4; c++) {
        int k0 = c * 256 + lane * 4;
        wvr[c] = *(const float4*)(wr_l + k0);
        wvz[c] = *(const float4*)(wz_l + k0);
        wvn[c] = *(const float4*)(wn_l + k0);
    }
    const float* wr_c = lWih + (size_t)j * 2048 + HH;        // h_h columns
    const float* wz_c = lWih + (size_t)(HH + j) * 2048 + HH;
    const float* wn_c = lWih + (size_t)(2 * HH + j) * 2048 + HH;

    float gr = 0.f, gz = 0.f, gn = 0.f;

    for (int s = 0; s < SEQ; ++s) {
        const int t = s & 3, blk = s >> 2;
        const float* hcur = hL + (s & 1) * (NB * HH);
        float* hnxt = hL + ((s + 1) & 1) * (NB * HH);

        const size_t m = (size_t)beta * SEQ + s;
        const float gxr = gix[m * H3 + j];
        const float gxz = gix[m * H3 + HH + j];
        const float gxn = gix[m * H3 + 2 * HH + j];

        // hsm already holds hL-buf0 at t==0 (staged during prev t==3 phase)
        if (s == 0 || t != 0) {
#pragma unroll
            for (int i = 0; i < 8; i++)
                ((float4*)hsm)[i * 256 + tid] = ((const float4*)hcur)[i * 256 + tid];
        }
        if (t == 0) {
            const float* hhc = hH + (blk & 1) * (NB * HH);
#pragma unroll
            for (int i = 0; i < 8; i++)
                ((float4*)hhm)[i * 256 + tid] = ((const float4*)hhc)[i * 256 + tid];
        }
        __syncthreads();

        if (t == 0) {
            // gih = h_h . l_Wih[:, H:2H] rows {j,H+j,2H+j} — once per block
            float ar[NB], az[NB], an[NB];
#pragma unroll
            for (int b = 0; b < NB; b++) { ar[b] = 0.f; az[b] = 0.f; an[b] = 0.f; }
#pragma unroll
            for (int c = 0; c < 4; c++) {
                int k0 = c * 256 + lane * 4;
                float4 vr = *(const float4*)(wr_c + k0);
                float4 vz = *(const float4*)(wz_c + k0);
                float4 vn = *(const float4*)(wn_c + k0);
#pragma unroll
                for (int b = 0; b < NB; b++) {
                    float4 hv = *(const float4*)(hhm + b * HH + k0);
                    ar[b] += vr.x * hv.x + vr.y * hv.y + vr.z * hv.z + vr.w * hv.w;
                    az[b] += vz.x * hv.x + vz.y * hv.y + vz.z * hv.z + vz.w * hv.w;
                    an[b] += vn.x * hv.x + vn.y * hv.y + vn.z * hv.z + vn.w * hv.w;
                }
            }
            gr = redScatter(ar, lane);
            gz = redScatter(az, lane);
            gn = redScatter(an, lane);
        }

        // gh = h_l . l_Whh rows (weights in registers)
        float pr[NB], pz[NB], pn[NB];
#pragma unroll
        for (int b = 0; b < NB; b++) { pr[b] = 0.f; pz[b] = 0.f; pn[b] = 0.f; }
#pragma unroll
        for (int c = 0; c < 4; c++) {
            int k0 = c * 256 + lane * 4;
            float4 vr = wvr[c], vz = wvz[c], vn = wvn[c];
#pragma unroll
            for (int b = 0; b < NB; b++) {
                float4 hv = *(const float4*)(hsm + b * HH + k0);
                pr[b] += vr.x * hv.x + vr.y * hv.y + vr.z * hv.z + vr.w * hv.w;
                pz[b] += vz.x * hv.x + vz.y * hv.y + vz.z * hv.z + vz.w * hv.w;
                pn[b] += vn.x * hv.x + vn.y * hv.y + vn.z * hv.z + vn.w * hv.w;
            }
        }
        float sr = redScatter(pr, lane);
        float sz = redScatter(pz, lane);
        float sn = redScatter(pn, lane);

        if (lane < NB) {
            float hr = sr + br, hz = sz + bz, hn = sn + bn;
            float r  = sigm(gxr + gr + hr);
            float z  = sigm(gxz + gz + hz);
            float n  = tanhf(gxn + gn + r * hn);
            float hold = hsm[beta * HH + j];
            float hnew = (1.f - z) * n + z * hold;
            hnxt[beta * HH + j] = hnew;
            hs[m * HH + j] = f2bf(hnew);
        }
        gbar(cnt, gen);

        if (t == 3) {
            // high GRU: h_h' = GRU(x = h_l_end (hL buf0), state = h_h (hhm))
            const float* hhc = hH + (blk & 1) * (NB * HH);
            float* hhn = hH + ((blk + 1) & 1) * (NB * HH);
            (void)hhc;
#pragma unroll
            for (int i = 0; i < 8; i++)
                ((float4*)hsm)[i * 256 + tid] = ((const float4*)hL)[i * 256 + tid];
            __syncthreads();
            const float* wir = hWih + (size_t)j * HH;
            const float* wiz = hWih + (size_t)(HH + j) * HH;
            const float* win = hWih + (size_t)(2 * HH + j) * HH;
            const float* whr = hWhh + (size_t)j * HH;
            const float* whz = hWhh + (size_t)(HH + j) * HH;
            const float* whn = hWhh + (size_t)(2 * HH + j) * HH;
            float air[NB], aiz[NB], ain[NB], ahr[NB], ahz[NB], ahn[NB];
#pragma unroll
            for (int b = 0; b < NB; b++) {
                air[b] = 0.f; aiz[b] = 0.f; ain[b] = 0.f;
                ahr[b] = 0.f; ahz[b] = 0.f; ahn[b] = 0.f;
            }
#pragma unroll
            for (int c = 0; c < 4; c++) {
                int k0 = c * 256 + lane * 4;
                float4 vir = *(const float4*)(wir + k0);
                float4 viz = *(const float4*)(wiz + k0);
                float4 vin = *(const float4*)(win + k0);
                float4 vhr = *(const float4*)(whr + k0);
                float4 vhz = *(const float4*)(whz + k0);
                float4 vhn = *(const float4*)(whn + k0);
#pragma unroll
                for (int b = 0; b < NB; b++) {
                    float4 xv = *(const float4*)(hsm + b * HH + k0);
                    float4 hv = *(const float4*)(hhm + b * HH + k0);
                    air[b] += vir.x * xv.x + vir.y * xv.y + vir.z * xv.z + vir.w * xv.w;
                    aiz[b] += viz.x * xv.x + viz.y * xv.y + viz.z * xv.z + viz.w * xv.w;
                    ain[b] += vin.x * xv.x + vin.y * xv.y + vin.z * xv.z + vin.w * xv.w;
                    ahr[b] += vhr.x * hv.x + vhr.y * hv.y + vhr.z * hv.z + vhr.w * hv.w;
                    ahz[b] += vhz.x * hv.x + vhz.y * hv.y + vhz.z * hv.z + vhz.w * hv.w;
                    ahn[b] += vhn.x * hv.x + vhn.y * hv.y + vhn.z * hv.z + vhn.w * hv.w;
                }
            }
            float sir  = redScatter(air, lane) + hbr;
            float siz  = redScatter(aiz, lane) + hbz;
            float sin_ = redScatter(ain, lane) + hbn;
            float shr  = redScatter(ahr, lane) + ghr;
            float shz  = redScatter(ahz, lane) + ghz;
            float shn  = redScatter(ahn, lane) + ghn;
            if (lane < NB) {
                float r = sigm(sir + shr);
                float z = sigm(siz + shz);
                float n = tanhf(sin_ + r * shn);
                float hnew = (1.f - z) * n + z * hhm[beta * HH + j];
                hhn[beta * HH + j] = hnew;
            }
            gbar(cnt, gen);
        }
    }
}

// ---------------------------------------------------------------------------
__global__ void kTail(const float* __restrict__ hl, const float* __restrict__ hh,
                      float* __restrict__ dst) {
    int i = blockIdx.x * 256 + threadIdx.x;
    if (i < NB * HH) dst[i] = hl[i];
    else if (i < 2 * NB * HH) dst[i] = hh[i - NB * HH];
}

// ---------------------------------------------------------------------------
extern "C" void kernel_launch(void* const* d_in, const int* in_sizes, int n_in,
                              void* d_out, int out_size, void* d_ws, size_t ws_size,
                              hipStream_t stream) {
    const int*   x    = (const int*)  d_in[0];
    const float* hl0  = (const float*)d_in[1];
    const float* hh0  = (const float*)d_in[2];
    const float* emb  = (const float*)d_in[3];
    const float* lWih = (const float*)d_in[4];   // [3072][2048]
    const float* lWhh = (const float*)d_in[5];   // [3072][1024]
    const float* lbih = (const float*)d_in[6];
    const float* lbhh = (const float*)d_in[7];
    const float* hWih = (const float*)d_in[8];
    const float* hWhh = (const float*)d_in[9];
    const float* hbih = (const float*)d_in[10];
    const float* hbhh = (const float*)d_in[11];
    const float* outW = (const float*)d_in[12];  // [32000][1024]
    const float* outb = (const float*)d_in[13];
    float* out = (float*)d_out;

    char* p = (char*)d_ws;
    float* gix = (float*)p;          p += (size_t)MTOK * H3 * 4;   // 25.2 MB
    float* hbufL = (float*)p;        p += 2 * (size_t)NB * HH * 4;
    float* hbufH = (float*)p;        p += 2 * (size_t)NB * HH * 4;
    unsigned* syncb = (unsigned*)p;  p += 256;
    uint16_t* hsb = (uint16_t*)p;    p += (size_t)MTOK * HH * 2;   // 4.2 MB
    uint16_t* xe = (uint16_t*)p;     p += (size_t)MTOK * HH * 2;
    uint16_t* lWihB = (uint16_t*)p;  p += (size_t)H3 * HH * 2;     // 6.3 MB
    uint16_t* outWB = (uint16_t*)p;  p += (size_t)VOCAB * HH * 2;  // 65.5 MB
    const bool bf16w = (size_t)(p - (char*)d_ws) <= ws_size;

    hipMemcpyAsync(hbufL, hl0, (size_t)NB * HH * 4, hipMemcpyDeviceToDevice, stream);
    hipMemcpyAsync(hbufH, hh0, (size_t)NB * HH * 4, hipMemcpyDeviceToDevice, stream);
    hipMemsetAsync(syncb, 0, 256, stream);

    kEmbed<<<MTOK, 256, 0, stream>>>(x, emb, xe);
    if (bf16w) {
        kConv<<<H3, 256, 0, stream>>>(lWih, lWihB, 2048);
        kGemm<<<dim3(H3 / 128, MTOK / 128), 256, 0, stream>>>(xe, lWihB, lbih, gix, H3);
    } else {
        kGemmF<<<dim3(H3 / 128, MTOK / 128), 256, 0, stream>>>(xe, lWih, lbih, gix, H3, 2048);
    }

    // entire 256-step hierarchical scan in one persistent kernel (normal launch)
    kScan<<<NWG, 256, 0, stream>>>(lWih, lWhh, lbhh, hWih, hWhh, hbih, hbhh,
                                   gix, hbufL, hbufH, hsb, syncb);

    if (bf16w) {
        kConv<<<VOCAB, 256, 0, stream>>>(outW, outWB, 1024);
        kGemm<<<dim3(VOCAB / 128, MTOK / 128), 256, 0, stream>>>(hsb, outWB, outb, out, VOCAB);
    } else {
        kGemmF<<<dim3(VOCAB / 128, MTOK / 128), 256, 0, stream>>>(hsb, outW, outb, out, VOCAB, 1024);
    }
    kTail<<<64, 256, 0, stream>>>(hbufL, hbufH, out + (size_t)MTOK * VOCAB);
}